// Round 7
// baseline (1663.581 us; speedup 1.0000x reference)
//
#include <hip/hip_runtime.h>
#include <cstdint>
#include <cstddef>

#define DEV __device__ __forceinline__

// ---------------- problem constants ----------------
constexpr size_t W_TOT = 131712;
constexpr size_t OFF_W1 = 0;       // [128][256]
constexpr size_t OFF_B1 = 32768;   // [256]
constexpr size_t OFF_W2 = 33024;   // [256][256]
constexpr size_t OFF_B2 = 98560;   // [256]
constexpr size_t OFF_W3 = 98816;   // [256][128]
constexpr size_t OFF_B3 = 131584;  // [128]

constexpr int OPS = 272;           // LDS activation row stride

// ---------------- workspace layout (floats) ----------------
constexpr size_t P_LOSS = 0;                    // [4][256]
constexpr size_t P_WA   = 1024;                 // [8][32]
constexpr size_t P_WU   = 1280;                 // [8][32]
constexpr size_t P_FT   = 1536;                 // [8]
constexpr size_t P_HP   = 2048;                 // [256][4]
constexpr size_t P_H2PI = 4096;                 // [256][128]
constexpr size_t P_KEYS = P_H2PI + 32768;       // [256][128]
constexpr size_t P_VALS = P_KEYS + 32768;       // [256][128]
constexpr size_t P_D3   = P_VALS + 32768;       // [256][128]
constexpr size_t P_H1   = P_D3 + 32768;         // [256][256]
constexpr size_t P_H2   = P_H1 + 65536;         // [256][256]
constexpr size_t P_D1   = P_H2 + 65536;         // [256][256]
constexpr size_t P_D2   = P_D1 + 65536;         // [256][256]
constexpr size_t P_STRUCT = P_D2 + 65536;       // [256][128]
constexpr size_t P_TRANS  = P_STRUCT + 32768;   // [256][16384]

DEV float sigm(float x) { return 1.f / (1.f + expf(-x)); }

// 256-thread WG sum; returns total to ALL threads.
DEV float wgsum256(float v, float* red) {
#pragma unroll
  for (int s = 32; s > 0; s >>= 1) v += __shfl_xor(v, s);
  if ((threadIdx.x & 63) == 0) red[threadIdx.x >> 6] = v;
  __syncthreads();
  const float t = red[0] + red[1] + red[2] + red[3];
  __syncthreads();
  return t;
}

// =========================================================================
// Dense layers, 256 threads, no spill (VGPR budget 256 at this block size).
// MLP latency fix: 4 independent in-thread K-segments, each 8-wide, double-
// buffered -> up to 64 weight loads in flight per thread.
// =========================================================================

// OUT=256: one col per thread. W row-major [IN][256].
template<int IN, int ROWS>
DEV void denseA(const float* __restrict__ W, const float* __restrict__ bias,
                const float* in, int ips, float* out, int ops, int relu)
{
  constexpr int SEG = IN / 4;
  constexpr int NIT = SEG / 8;
  const int j = (int)threadIdx.x;
  float w0[4][8], w1[4][8];
  float acc[4][ROWS];
#pragma unroll
  for (int s = 0; s < 4; ++s)
#pragma unroll
    for (int r = 0; r < ROWS; ++r) acc[s][r] = 0.f;
#pragma unroll
  for (int s = 0; s < 4; ++s)
#pragma unroll
    for (int u = 0; u < 8; ++u)
      w0[s][u] = W[(size_t)(s * SEG + u) * 256 + j];
#pragma unroll
  for (int t = 1; t <= NIT; ++t) {
    if (t < NIT) {
#pragma unroll
      for (int s = 0; s < 4; ++s)
#pragma unroll
        for (int u = 0; u < 8; ++u)
          w1[s][u] = W[(size_t)(s * SEG + t * 8 + u) * 256 + j];
    }
#pragma unroll
    for (int s = 0; s < 4; ++s)
#pragma unroll
      for (int u = 0; u < 8; ++u)
#pragma unroll
        for (int r = 0; r < ROWS; ++r)
          acc[s][r] = fmaf(in[r * ips + s * SEG + (t - 1) * 8 + u], w0[s][u], acc[s][r]);
    if (t < NIT) {
#pragma unroll
      for (int s = 0; s < 4; ++s)
#pragma unroll
        for (int u = 0; u < 8; ++u)
          w0[s][u] = w1[s][u];
    }
  }
#pragma unroll
  for (int r = 0; r < ROWS; ++r) {
    float v = acc[0][r] + acc[1][r] + acc[2][r] + acc[3][r] + (bias ? bias[j] : 0.f);
    if (relu) v = fmaxf(v, 0.f);
    out[r * ops + j] = v;
  }
  __syncthreads();
}

// OUT=128: col j=tid&127, 2-way cross-thread K-split + in-thread segments.
template<int IN, int ROWS>
DEV void denseB(const float* __restrict__ W, const float* __restrict__ bias,
                const float* in, int ips, float* out, int ops, int relu,
                float* scr)
{
  constexpr int HK = IN / 2;
  constexpr int NSEG = (HK >= 128) ? 4 : 2;
  constexpr int SEG = HK / NSEG;
  constexpr int NIT = SEG / 8;
  const int j = (int)threadIdx.x & 127;
  const int half = (int)threadIdx.x >> 7;
  const int kb = half * HK;
  float w0[NSEG][8], w1[NSEG][8];
  float acc[NSEG][ROWS];
#pragma unroll
  for (int s = 0; s < NSEG; ++s)
#pragma unroll
    for (int r = 0; r < ROWS; ++r) acc[s][r] = 0.f;
#pragma unroll
  for (int s = 0; s < NSEG; ++s)
#pragma unroll
    for (int u = 0; u < 8; ++u)
      w0[s][u] = W[(size_t)(kb + s * SEG + u) * 128 + j];
#pragma unroll
  for (int t = 1; t <= NIT; ++t) {
    if (t < NIT) {
#pragma unroll
      for (int s = 0; s < NSEG; ++s)
#pragma unroll
        for (int u = 0; u < 8; ++u)
          w1[s][u] = W[(size_t)(kb + s * SEG + t * 8 + u) * 128 + j];
    }
#pragma unroll
    for (int s = 0; s < NSEG; ++s)
#pragma unroll
      for (int u = 0; u < 8; ++u)
#pragma unroll
        for (int r = 0; r < ROWS; ++r)
          acc[s][r] = fmaf(in[r * ips + kb + s * SEG + (t - 1) * 8 + u], w0[s][u], acc[s][r]);
    if (t < NIT) {
#pragma unroll
      for (int s = 0; s < NSEG; ++s)
#pragma unroll
        for (int u = 0; u < 8; ++u)
          w0[s][u] = w1[s][u];
    }
  }
#pragma unroll
  for (int r = 0; r < ROWS; ++r) {
    float t0 = 0.f;
#pragma unroll
    for (int s = 0; s < NSEG; ++s) t0 += acc[s][r];
    scr[(half * ROWS + r) * 128 + j] = t0;
  }
  __syncthreads();
  if ((int)threadIdx.x < 128 * ROWS) {
    const int r = (int)threadIdx.x >> 7, jj = (int)threadIdx.x & 127;
    float v = scr[(0 * ROWS + r) * 128 + jj] + scr[(1 * ROWS + r) * 128 + jj] +
              (bias ? bias[jj] : 0.f);
    if (relu) v = fmaxf(v, 0.f);
    out[r * ops + jj] = v;
  }
  __syncthreads();
}

// q1 = sRow @ wq[0:128]; q2 = eRow @ wq[128:256]; thread-half per stream.
DEV void lay_q12_256(const float* sRow, const float* eRow,
                     const float* __restrict__ wq, float* q12)
{
  const int j = (int)threadIdx.x & 127;
  const int which = (int)threadIdx.x >> 7;
  const float* src = which ? eRow : sRow;
  const int rb = which * 128;
  float w0[2][8], w1[2][8], acc[2] = { 0.f, 0.f };
#pragma unroll
  for (int s = 0; s < 2; ++s)
#pragma unroll
    for (int u = 0; u < 8; ++u)
      w0[s][u] = wq[(size_t)(rb + s * 64 + u) * 128 + j];
#pragma unroll
  for (int t = 1; t <= 8; ++t) {
    if (t < 8) {
#pragma unroll
      for (int s = 0; s < 2; ++s)
#pragma unroll
        for (int u = 0; u < 8; ++u)
          w1[s][u] = wq[(size_t)(rb + s * 64 + t * 8 + u) * 128 + j];
    }
#pragma unroll
    for (int s = 0; s < 2; ++s)
#pragma unroll
      for (int u = 0; u < 8; ++u)
        acc[s] = fmaf(src[s * 64 + (t - 1) * 8 + u], w0[s][u], acc[s]);
    if (t < 8) {
#pragma unroll
      for (int s = 0; s < 2; ++s)
#pragma unroll
        for (int u = 0; u < 8; ++u)
          w0[s][u] = w1[s][u];
    }
  }
  q12[which * OPS + j] = acc[0] + acc[1];
  __syncthreads();
}

// keys (threads 0-127, wk) and vals (threads 128-255, wv) from [fS|eR].
DEV void lay_kv_256(const float* fS, const float* eR,
                    const float* __restrict__ wk, const float* __restrict__ wv,
                    float* gK, float* gV, int g)
{
  const int j = (int)threadIdx.x & 127;
  const int which = (int)threadIdx.x >> 7;
  const float* W = which ? wv : wk;
  float w0[4][8], w1[4][8], acc[4] = { 0.f, 0.f, 0.f, 0.f };
#pragma unroll
  for (int s = 0; s < 4; ++s)
#pragma unroll
    for (int u = 0; u < 8; ++u)
      w0[s][u] = W[(size_t)(s * 64 + u) * 128 + j];
#pragma unroll
  for (int t = 1; t <= 8; ++t) {
    if (t < 8) {
#pragma unroll
      for (int s = 0; s < 4; ++s)
#pragma unroll
        for (int u = 0; u < 8; ++u)
          w1[s][u] = W[(size_t)(s * 64 + t * 8 + u) * 128 + j];
    }
#pragma unroll
    for (int s = 0; s < 4; ++s) {
      const float* sp = (s < 2) ? fS + s * 64 : eR + (s - 2) * 64;
#pragma unroll
      for (int u = 0; u < 8; ++u)
        acc[s] = fmaf(sp[(t - 1) * 8 + u], w0[s][u], acc[s]);
    }
    if (t < 8) {
#pragma unroll
      for (int s = 0; s < 4; ++s)
#pragma unroll
        for (int u = 0; u < 8; ++u)
          w0[s][u] = w1[s][u];
    }
  }
  (which ? gV : gK)[(size_t)g * 128 + j] = acc[0] + acc[1] + acc[2] + acc[3];
}

// de[128] @ dec_w[128x512] vs sens: thread handles cols j and j+256.
DEV float decloss256(const float* de, const float* __restrict__ dec_w,
                     const float* sens)
{
  const int j = (int)threadIdx.x;
  float w0[2][8], w1[2][8];
  float a0 = 0.f, a1 = 0.f;
#pragma unroll
  for (int c = 0; c < 2; ++c)
#pragma unroll
    for (int u = 0; u < 8; ++u)
      w0[c][u] = dec_w[(size_t)u * 512 + j + c * 256];
#pragma unroll
  for (int t = 1; t <= 16; ++t) {
    if (t < 16) {
#pragma unroll
      for (int c = 0; c < 2; ++c)
#pragma unroll
        for (int u = 0; u < 8; ++u)
          w1[c][u] = dec_w[(size_t)(t * 8 + u) * 512 + j + c * 256];
    }
#pragma unroll
    for (int u = 0; u < 8; ++u) {
      const float x = de[(t - 1) * 8 + u];
      a0 = fmaf(x, w0[0][u], a0);
      a1 = fmaf(x, w0[1][u], a1);
    }
    if (t < 16) {
#pragma unroll
      for (int c = 0; c < 2; ++c)
#pragma unroll
        for (int u = 0; u < 8; ++u)
          w0[c][u] = w1[c][u];
    }
  }
  const float d0 = a0 - sens[j];
  const float d1 = a1 - sens[j + 256];
  return d0 * d0 + d1 * d1;
}

// ================= K1a: action MLP first two layers =================
__global__ __launch_bounds__(128) void k_pi_h2(
    const float* __restrict__ actions,
    const float* __restrict__ w1, const float* __restrict__ b1,
    const float* __restrict__ w2, const float* __restrict__ b2,
    float* __restrict__ h2out)
{
  const int row = blockIdx.x;
  const int j = threadIdx.x;
  __shared__ float a[32];
  __shared__ float h1[128];
  if (j < 32) a[j] = actions[row * 32 + j];
  __syncthreads();
  float acc = b1[j];
#pragma unroll
  for (int i = 0; i < 32; ++i) acc = fmaf(a[i], w1[i * 128 + j], acc);
  h1[j] = fmaxf(acc, 0.f);
  __syncthreads();
  float acc2 = b2[j];
#pragma unroll 8
  for (int i = 0; i < 128; ++i) acc2 = fmaf(h1[i], w2[i * 128 + j], acc2);
  h2out[row * 128 + j] = fmaxf(acc2, 0.f);
}

// ================= K1b: h2[256,128] @ W3[128,16384] =================
__global__ __launch_bounds__(256) void k_pi_trans(
    const float* __restrict__ h2,
    const float* __restrict__ w3, const float* __restrict__ b3,
    float* __restrict__ trans)
{
  const int col = blockIdx.x * 256 + threadIdx.x;
  const int r0 = blockIdx.y * 32;
  __shared__ float h2s[32][128];
  for (int idx = threadIdx.x; idx < 32 * 128; idx += 256)
    h2s[idx >> 7][idx & 127] = h2[(size_t)(r0 + (idx >> 7)) * 128 + (idx & 127)];
  __syncthreads();
  float acc[32];
#pragma unroll
  for (int r = 0; r < 32; ++r) acc[r] = 0.f;
  for (int i = 0; i < 128; i += 8) {
    float w[8];
#pragma unroll
    for (int c = 0; c < 8; ++c) w[c] = w3[(size_t)(i + c) * 16384 + col];
#pragma unroll
    for (int r = 0; r < 32; ++r) {
      float s = acc[r];
#pragma unroll
      for (int c = 0; c < 8; ++c) s = fmaf(h2s[r][i + c], w[c], s);
      acc[r] = s;
    }
  }
  const float bv = b3[col];
#pragma unroll
  for (int r = 0; r < 32; ++r)
    trans[(size_t)(r0 + r) * 16384 + col] = acc[r] + bv;
}

// ================= K2: RNN scan with next-step prefetch =================
__global__ __launch_bounds__(512) void k_rnn(
    const float* __restrict__ trans, const float* __restrict__ rinit,
    float* __restrict__ structural)
{
  const int b = blockIdx.x;
  const int tid = threadIdx.x;
  const int j = tid & 127, seg = tid >> 7;
  __shared__ float h[128];
  __shared__ float part[4][128];
  __shared__ float ssq;
  if (tid < 128) h[tid] = rinit[tid];
  __syncthreads();
  if (tid < 64) {
    float v = h[tid] * h[tid] + h[tid + 64] * h[tid + 64];
#pragma unroll
    for (int s = 32; s > 0; s >>= 1) v += __shfl_xor(v, s);
    if (tid == 0) ssq = v;
  }
  __syncthreads();
  if (tid < 128) h[tid] /= fmaxf(sqrtf(ssq), 1e-12f);
  __syncthreads();

  float cur[32], nxt[32];
  {
    const float* T0 = trans + ((size_t)(b * 32) << 14);
#pragma unroll
    for (int k = 0; k < 32; ++k) cur[k] = T0[(size_t)(seg * 32 + k) * 128 + j];
  }
  for (int t = 0; t < 32; ++t) {
    if (t < 31) {
      const float* Tn = trans + ((size_t)(b * 32 + t + 1) << 14);
#pragma unroll
      for (int k = 0; k < 32; ++k) nxt[k] = Tn[(size_t)(seg * 32 + k) * 128 + j];
    }
    float acc = 0.f;
#pragma unroll
    for (int k = 0; k < 32; ++k) acc = fmaf(h[seg * 32 + k], cur[k], acc);
    part[seg][j] = acc;
    __syncthreads();
    if (tid < 128) {
      float r = fmaxf(part[0][j] + part[1][j] + part[2][j] + part[3][j], 0.f);
      part[0][j] = r;
    }
    __syncthreads();
    if (tid < 64) {
      float v = part[0][tid] * part[0][tid] + part[0][tid + 64] * part[0][tid + 64];
#pragma unroll
      for (int s = 32; s > 0; s >>= 1) v += __shfl_xor(v, s);
      if (tid == 0) ssq = v;
    }
    __syncthreads();
    if (tid < 128) {
      const float nv = part[0][j] / fmaxf(sqrtf(ssq), 1e-12f);
      h[j] = nv;
      structural[(size_t)(b * 32 + t) * 128 + j] = nv;
    }
    __syncthreads();
    if (t < 31) {
#pragma unroll
      for (int k = 0; k < 32; ++k) cur[k] = nxt[k];
    }
  }
}

// ================= kChain: enc + r1..r4 + pv + all losses + keys/vals/hp =================
// 256 threads/WG: known-good codegen (VGPR<=256, no scratch spill).
__global__ __launch_bounds__(256) void kChain(
    const float* __restrict__ sensory, const float* __restrict__ structural_,
    const float* __restrict__ enc_w, const float* __restrict__ wq,
    const float* __restrict__ dec_w,
    const float* __restrict__ mw1, const float* __restrict__ mb1,
    const float* __restrict__ mw2, const float* __restrict__ mb2,
    const float* __restrict__ mw3, const float* __restrict__ mb3,
    const float* __restrict__ ow1, const float* __restrict__ ob1,
    const float* __restrict__ ow2, const float* __restrict__ ob2,
    const float* __restrict__ ow3, const float* __restrict__ ob3,
    const float* __restrict__ vw1, const float* __restrict__ vb1,
    const float* __restrict__ vw2, const float* __restrict__ vb2,
    const float* __restrict__ vw3, const float* __restrict__ vb3,
    const float* __restrict__ wk, const float* __restrict__ wv,
    const float* __restrict__ w_hp, const float* __restrict__ ir,
    float* __restrict__ gKeys, float* __restrict__ gVals,
    float* __restrict__ gHp, float* __restrict__ lossPart)
{
  const int g = blockIdx.x, tid = threadIdx.x;
  __shared__ float sens[512], sRow[128], eRow[128], dgsRow[128], cRow[128], infRow[128];
  __shared__ float cbuf[256];
  __shared__ float actA[2 * OPS], actB[2 * OPS];
  __shared__ float scr[512];
  __shared__ float red[4];

  for (int i = tid; i < 512; i += 256) sens[i] = sensory[(size_t)g * 512 + i];
  if (tid < 128) sRow[tid] = structural_[(size_t)g * 128 + tid];
  __syncthreads();

  // enc = sens @ enc_w
  denseB<512, 1>(enc_w, nullptr, sens, 0, eRow, 0, 0, scr);

  // ---- retrieve 1+2 paired (2 rows share the weight stream) ----
  lay_q12_256(sRow, eRow, wq, actA);
  denseA<128, 2>(mw1, mb1, actA, OPS, actB, OPS, 1);
  denseA<256, 2>(mw2, mb2, actB, OPS, actA, OPS, 1);
  denseB<256, 2>(mw3, mb3, actA, OPS, actB, OPS, 0, scr);
  denseA<128, 2>(ow1, ob1, actB, OPS, actA, OPS, 1);
  denseA<256, 2>(ow2, ob2, actA, OPS, actB, OPS, 1);
  denseA<256, 2>(ow3, ob3, actB, OPS, actA, OPS, 0);
  // actA row0 = [dgs|dec_enc], row1 = [dec_s2|*]
  float lrel = 0.f;
  if (tid < 128) {
    dgsRow[tid] = actA[tid];
    const float d = actA[OPS + tid] - sRow[tid];
    lrel = d * d;
  }
  const float relT = wgsum256(lrel, red);
  if (tid == 0) lossPart[256 + g] = relT;
  const float genT = wgsum256(decloss256(&actA[128], dec_w, sens), red);
  if (tid == 0) lossPart[g] = genT;

  // ---- retrieve 3 ----
  cbuf[tid] = (tid < 128) ? dgsRow[tid] : eRow[tid - 128];
  __syncthreads();
  denseB<256, 1>(wq, nullptr, cbuf, 0, actA, 0, 0, scr);    // q3
  denseA<128, 1>(mw1, mb1, actA, 0, actB, 0, 1);
  denseA<256, 1>(mw2, mb2, actB, 0, actA, 0, 1);
  denseB<256, 1>(mw3, mb3, actA, 0, actB, 0, 0, scr);
  denseA<128, 1>(ow1, ob1, actB, 0, actA, 0, 1);
  denseA<256, 1>(ow2, ob2, actA, 0, actB, 0, 1);
  denseA<256, 1>(ow3, ob3, actB, 0, actA, 0, 0);            // [corr|corr_e]
  float ls = 0.f;
  if (tid < 128) {
    cRow[tid] = actA[tid];
    const float d = actA[128 + tid] - eRow[tid];
    ls = d * d;
  }
  const float sseV = wgsum256(ls, red);

  // ---- pred_var ----
  cbuf[tid] = (tid < 128) ? cRow[tid] : dgsRow[tid - 128];
  __syncthreads();
  denseA<256, 1>(vw1, vb1, cbuf, 0, actB, 0, 0);
  actB[tid] = fmaxf(actB[tid] + sseV * vw1[(size_t)256 * 256 + tid], 0.f);
  __syncthreads();
  denseA<256, 1>(vw2, vb2, actB, 0, actA, 0, 1);
  denseB<256, 1>(vw3, vb3, actA, 0, actB, 0, 0, scr);       // pv in actB[0:128]
  const float sig = sigm(ir[0]);
  float lc = 0.f;
  if (tid < 128) {
    const float diff = (cRow[tid] - dgsRow[tid]) * sig * actB[tid];
    infRow[tid] = dgsRow[tid] + diff;
    lc = diff * diff;
  }
  const float consT = wgsum256(lc, red);
  if (tid == 0) lossPart[512 + g] = consT;
  __syncthreads();

  // ---- retrieve 4 ----
  denseB<128, 1>(wq, nullptr, infRow, 0, actA, 0, 0, scr);  // q4 (wq rows 0-127)
  denseA<128, 1>(mw1, mb1, actA, 0, actB, 0, 1);
  denseA<256, 1>(mw2, mb2, actB, 0, actA, 0, 1);
  denseB<256, 1>(mw3, mb3, actA, 0, actB, 0, 0, scr);
  denseA<128, 1>(ow1, ob1, actB, 0, actA, 0, 1);
  denseA<256, 1>(ow2, ob2, actA, 0, actB, 0, 1);
  denseA<256, 1>(ow3, ob3, actB, 0, actA, 0, 0);            // [finalS|inf_e]
  const float infT = wgsum256(decloss256(&actA[128], dec_w, sens), red);
  if (tid == 0) lossPart[768 + g] = infT;

  // ---- keys / vals / hp ----
  lay_kv_256(actA, eRow, wk, wv, gKeys, gVals, g);
  const int c = tid >> 6, l = tid & 63;
  float acc = 0.f;
  if (c < 3) {
    for (int i = l; i < 256; i += 64) {
      const float x = (i < 128) ? actA[i] : eRow[i - 128];
      acc = fmaf(x, w_hp[i * 3 + c], acc);
    }
  }
#pragma unroll
  for (int s = 32; s > 0; s >>= 1) acc += __shfl_xor(acc, s);
  if (c < 3 && l == 0) gHp[(size_t)g * 4 + c] = acc;
}

// ================= kD: meta fwd/bwd (blocks 0-255) + coef scan (block 256) =================
__global__ __launch_bounds__(256) void kD(
    const float* __restrict__ gKeys, const float* __restrict__ gVals,
    const float* __restrict__ gHp,
    const float* __restrict__ mw1, const float* __restrict__ mb1,
    const float* __restrict__ mw2, const float* __restrict__ mb2,
    const float* __restrict__ mw3, const float* __restrict__ mb3,
    float* __restrict__ ws_h1, float* __restrict__ ws_h2,
    float* __restrict__ ws_d1, float* __restrict__ ws_d2, float* __restrict__ ws_d3,
    float* __restrict__ wA, float* __restrict__ wU, float* __restrict__ Ft)
{
  const int tid = threadIdx.x;
  __shared__ float kRow[128], vRow[128];
  __shared__ float actA[256], actB[256], d3R[128], d2R[256];
  __shared__ float scr[512];
  __shared__ float lr[256], sf[256], sb[256];
  if (blockIdx.x == 256) {
    lr[tid] = gHp[(size_t)tid * 4 + 0];
    sf[tid] = sigm(gHp[(size_t)tid * 4 + 1]);
    sb[tid] = sigm(gHp[(size_t)tid * 4 + 2]);
    __syncthreads();
    if (tid < 8) {
      const int b = tid;
      float cB = 1.f, cF = 1.f, Bv = 1.f;
      wU[b * 32 + 31] = lr[b * 32 + 31];
      wA[b * 32 + 31] = lr[b * 32 + 31];
      for (int t = 30; t >= 0; --t) {
        cB = sb[b * 32 + t + 1] * cB;
        cF = sf[b * 32 + t + 1] * cF;
        Bv = cF + sb[b * 32 + t + 1] * Bv;
        wU[b * 32 + t] = lr[b * 32 + t] * cB;
        wA[b * 32 + t] = lr[b * 32 + t] * Bv;
      }
      float ft = 1.f;
      for (int t = 0; t < 32; ++t) ft *= sf[b * 32 + t];
      Ft[b] = ft;
    }
    return;
  }
  const int g = blockIdx.x;
  if (tid < 128) kRow[tid] = gKeys[(size_t)g * 128 + tid];
  else vRow[tid - 128] = gVals[(size_t)g * 128 + (tid - 128)];
  __syncthreads();
  denseA<128, 1>(mw1, mb1, kRow, 0, actA, 0, 1);
  ws_h1[(size_t)g * 256 + tid] = actA[tid];
  denseA<256, 1>(mw2, mb2, actA, 0, actB, 0, 1);
  ws_h2[(size_t)g * 256 + tid] = actB[tid];
  denseB<256, 1>(mw3, mb3, actB, 0, d3R, 0, 0, scr);
  if (tid < 128) {
    const float d = (d3R[tid] - vRow[tid]) * (2.f / 128.f);
    d3R[tid] = d;
    ws_d3[(size_t)g * 128 + tid] = d;
  }
  __syncthreads();
  // d2 = relu'(h2) * (mw3 row j . d3)
  {
    const int j = tid;
    float acc = 0.f;
    for (int jc = 0; jc < 128; jc += 4) {
      const float4 w = *reinterpret_cast<const float4*>(&mw3[(size_t)j * 128 + jc]);
      acc = fmaf(w.x, d3R[jc + 0], acc);
      acc = fmaf(w.y, d3R[jc + 1], acc);
      acc = fmaf(w.z, d3R[jc + 2], acc);
      acc = fmaf(w.w, d3R[jc + 3], acc);
    }
    const float v = (actB[j] > 0.f) ? acc : 0.f;
    d2R[j] = v;
    ws_d2[(size_t)g * 256 + j] = v;
  }
  __syncthreads();
  // d1 = relu'(h1) * (mw2 row j . d2)
  {
    const int j = tid;
    float acc = 0.f;
    for (int jc = 0; jc < 256; jc += 4) {
      const float4 w = *reinterpret_cast<const float4*>(&mw2[(size_t)j * 256 + jc]);
      acc = fmaf(w.x, d2R[jc + 0], acc);
      acc = fmaf(w.y, d2R[jc + 1], acc);
      acc = fmaf(w.z, d2R[jc + 2], acc);
      acc = fmaf(w.w, d2R[jc + 3], acc);
    }
    ws_d1[(size_t)g * 256 + j] = (actA[j] > 0.f) ? acc : 0.f;
  }
}

// ================= kW: outer products + bias + final =================
DEV void outer_body(const float* __restrict__ L, int Lld,
                    const float* __restrict__ D, int Dld,
                    const float* __restrict__ P,
                    const float* __restrict__ wA, const float* __restrict__ wU,
                    const float* __restrict__ Ftot,
                    float* __restrict__ out, size_t regionOff, int J,
                    int b, int i0, float* __restrict__ wAk, float* __restrict__ wUk)
{
  const int tid = threadIdx.x;
  for (int idx = tid; idx < 1024; idx += 256) {
    const int t = idx >> 5, ii = idx & 31;
    const float kv = L[(size_t)(b * 32 + t) * Lld + i0 + ii];
    wAk[t * 33 + ii] = wA[b * 32 + t] * kv;
    wUk[t * 33 + ii] = wU[b * 32 + t] * kv;
  }
  __syncthreads();
  const int j = (J == 256) ? tid : (tid & 127);
  const int g2 = (J == 256) ? 0 : (tid >> 7);
  const int span = (J == 256) ? 32 : 16;
  const int iBeg = g2 * span;
  float dv[32];
#pragma unroll
  for (int t = 0; t < 32; ++t) dv[t] = D[(size_t)(b * 32 + t) * Dld + j];
  const float ft = Ftot[b];
  float* ob = out + 1 + (size_t)b * (2 * W_TOT);
  for (int ii = iBeg; ii < iBeg + span; ++ii) {
    float aA = 0.f, aU = 0.f;
#pragma unroll
    for (int t = 0; t < 32; ++t) {
      aA = fmaf(wAk[t * 33 + ii], dv[t], aA);
      aU = fmaf(wUk[t * 33 + ii], dv[t], aU);
    }
    const int i = i0 + ii;
    const size_t w = regionOff + (size_t)i * J + j;
    ob[w] = ft * P[(size_t)i * J + j] - aA;
    ob[W_TOT + w] = aU;
  }
}

__global__ __launch_bounds__(256) void kW(
    const float* __restrict__ keys, const float* __restrict__ h1,
    const float* __restrict__ h2, const float* __restrict__ d1,
    const float* __restrict__ d2, const float* __restrict__ d3,
    const float* __restrict__ mw1, const float* __restrict__ mb1,
    const float* __restrict__ mw2, const float* __restrict__ mb2,
    const float* __restrict__ mw3, const float* __restrict__ mb3,
    const float* __restrict__ wA, const float* __restrict__ wU,
    const float* __restrict__ Ft, const float* __restrict__ lossPart,
    float* __restrict__ out)
{
  __shared__ float wAk[32 * 33], wUk[32 * 33];
  __shared__ float red[4];
  const int bid = blockIdx.x;
  const int tid = threadIdx.x;
  if (bid < 32) {
    outer_body(keys, 128, d1, 256, mw1, wA, wU, Ft, out, OFF_W1, 256,
               bid >> 2, (bid & 3) * 32, wAk, wUk);
  } else if (bid < 96) {
    const int x = bid - 32;
    outer_body(h1, 256, d2, 256, mw2, wA, wU, Ft, out, OFF_W2, 256,
               x >> 3, (x & 7) * 32, wAk, wUk);
  } else if (bid < 160) {
    const int x = bid - 96;
    outer_body(h2, 256, d3, 128, mw3, wA, wU, Ft, out, OFF_W3, 128,
               x >> 3, (x & 7) * 32, wAk, wUk);
  } else if (bid < 168) {
    const int b = bid - 160;
    const float ft = Ft[b];
    float* ob = out + 1 + (size_t)b * (2 * W_TOT);
    for (int idx = tid; idx < 640; idx += 256) {
      const float* D; int ld, j; size_t off; float pv;
      if (idx < 256)      { D = d1; ld = 256; j = idx;       off = OFF_B1; pv = mb1[j]; }
      else if (idx < 512) { D = d2; ld = 256; j = idx - 256; off = OFF_B2; pv = mb2[j]; }
      else                { D = d3; ld = 128; j = idx - 512; off = OFF_B3; pv = mb3[j]; }
      float aA = 0.f, aU = 0.f;
#pragma unroll
      for (int t = 0; t < 32; ++t) {
        const float dv = D[(size_t)(b * 32 + t) * ld + j];
        aA = fmaf(wA[b * 32 + t], dv, aA);
        aU = fmaf(wU[b * 32 + t], dv, aU);
      }
      ob[off + j] = ft * pv - aA;
      ob[W_TOT + off + j] = aU;
    }
  } else {
    const int c = tid >> 6, l = tid & 63;
    float v = lossPart[c * 256 + l] + lossPart[c * 256 + 64 + l] +
              lossPart[c * 256 + 128 + l] + lossPart[c * 256 + 192 + l];
#pragma unroll
    for (int s = 32; s > 0; s >>= 1) v += __shfl_xor(v, s);
    if (l == 0) red[c] = v;
    __syncthreads();
    if (tid == 0) {
      const float i1 = 1.f / (256.f * 512.f);
      const float i2 = 1.f / (256.f * 128.f);
      out[0] = red[0] * i1 + 2.f * red[1] * i2 + red[2] * i2 + red[3] * i1;
    }
  }
}

// ================= launch =================
extern "C" void kernel_launch(void* const* d_in, const int* in_sizes, int n_in,
                              void* d_out, int out_size, void* d_ws, size_t ws_size,
                              hipStream_t stream)
{
  const float* sensory = (const float*)d_in[0];
  const float* actions = (const float*)d_in[1];
  const float* enc_w = (const float*)d_in[2];
  const float* dec_w = (const float*)d_in[3];
  const float* pi_w1 = (const float*)d_in[4];
  const float* pi_b1 = (const float*)d_in[5];
  const float* pi_w2 = (const float*)d_in[6];
  const float* pi_b2 = (const float*)d_in[7];
  const float* pi_w3 = (const float*)d_in[8];
  const float* pi_b3 = (const float*)d_in[9];
  const float* rinit = (const float*)d_in[10];
  const float* wq = (const float*)d_in[11];
  const float* wk = (const float*)d_in[12];
  const float* wv = (const float*)d_in[13];
  const float* w_hp = (const float*)d_in[14];
  const float* mw1 = (const float*)d_in[15]; const float* mb1 = (const float*)d_in[16];
  const float* mw2 = (const float*)d_in[17]; const float* mb2 = (const float*)d_in[18];
  const float* mw3 = (const float*)d_in[19]; const float* mb3 = (const float*)d_in[20];
  const float* ow1 = (const float*)d_in[21]; const float* ob1 = (const float*)d_in[22];
  const float* ow2 = (const float*)d_in[23]; const float* ob2 = (const float*)d_in[24];
  const float* ow3 = (const float*)d_in[25]; const float* ob3 = (const float*)d_in[26];
  const float* vw1 = (const float*)d_in[27]; const float* vb1 = (const float*)d_in[28];
  const float* vw2 = (const float*)d_in[29]; const float* vb2 = (const float*)d_in[30];
  const float* vw3 = (const float*)d_in[31]; const float* vb3 = (const float*)d_in[32];
  const float* ir  = (const float*)d_in[33];

  float* ws  = (float*)d_ws;
  float* out = (float*)d_out;

  float* lossP = ws + P_LOSS;
  float* wA = ws + P_WA; float* wU = ws + P_WU; float* Ft = ws + P_FT;
  float* hp = ws + P_HP;
  float* h2pi = ws + P_H2PI;
  float* keys = ws + P_KEYS;
  float* vals = ws + P_VALS;
  float* d3s = ws + P_D3;
  float* h1s = ws + P_H1;
  float* h2s = ws + P_H2;
  float* d1s = ws + P_D1;
  float* d2s = ws + P_D2;
  float* structural = ws + P_STRUCT;
  float* trans = ws + P_TRANS;

  hipLaunchKernelGGL(k_pi_h2, dim3(256), dim3(128), 0, stream,
                     actions, pi_w1, pi_b1, pi_w2, pi_b2, h2pi);
  hipLaunchKernelGGL(k_pi_trans, dim3(64, 8), dim3(256), 0, stream,
                     h2pi, pi_w3, pi_b3, trans);
  hipLaunchKernelGGL(k_rnn, dim3(8), dim3(512), 0, stream, trans, rinit, structural);
  hipLaunchKernelGGL(kChain, dim3(256), dim3(256), 0, stream,
                     sensory, structural, enc_w, wq, dec_w,
                     mw1, mb1, mw2, mb2, mw3, mb3,
                     ow1, ob1, ow2, ob2, ow3, ob3,
                     vw1, vb1, vw2, vb2, vw3, vb3,
                     wk, wv, w_hp, ir, keys, vals, hp, lossP);
  hipLaunchKernelGGL(kD, dim3(257), dim3(256), 0, stream,
                     keys, vals, hp, mw1, mb1, mw2, mb2, mw3, mb3,
                     h1s, h2s, d1s, d2s, d3s, wA, wU, Ft);
  hipLaunchKernelGGL(kW, dim3(169), dim3(256), 0, stream,
                     keys, h1s, h2s, d1s, d2s, d3s,
                     mw1, mb1, mw2, mb2, mw3, mb3,
                     wA, wU, Ft, lossP, out);
}

// Round 8
// 289.828 us; speedup vs baseline: 5.7399x; 5.7399x over previous
//
#include <hip/hip_runtime.h>
#include <cstdint>
#include <cstddef>

#define DEV __device__ __forceinline__

// ---------------- problem constants ----------------
constexpr size_t W_TOT = 131712;
constexpr size_t OFF_W1 = 0;       // [128][256]
constexpr size_t OFF_B1 = 32768;   // [256]
constexpr size_t OFF_W2 = 33024;   // [256][256]
constexpr size_t OFF_B2 = 98560;   // [256]
constexpr size_t OFF_W3 = 98816;   // [256][128]
constexpr size_t OFF_B3 = 131584;  // [128]

constexpr int OPS = 272;           // LDS activation row stride

// ---------------- workspace layout (floats) ----------------
constexpr size_t P_LOSS = 0;                    // [4][256]
constexpr size_t P_WA   = 1024;                 // [8][32]
constexpr size_t P_WU   = 1280;                 // [8][32]
constexpr size_t P_FT   = 1536;                 // [8]
constexpr size_t P_HP   = 2048;                 // [256][4]
constexpr size_t P_H2PI = 4096;                 // [256][128]
constexpr size_t P_KEYS = P_H2PI + 32768;       // [256][128]
constexpr size_t P_VALS = P_KEYS + 32768;       // [256][128]
constexpr size_t P_D3   = P_VALS + 32768;       // [256][128]
constexpr size_t P_H1   = P_D3 + 32768;         // [256][256]
constexpr size_t P_H2   = P_H1 + 65536;         // [256][256]
constexpr size_t P_D1   = P_H2 + 65536;         // [256][256]
constexpr size_t P_D2   = P_D1 + 65536;         // [256][256]
constexpr size_t P_STRUCT = P_D2 + 65536;       // [256][128]
constexpr size_t P_TRANS  = P_STRUCT + 32768;   // [256][16384]

DEV float sigm(float x) { return 1.f / (1.f + expf(-x)); }

// 256-thread WG sum; returns total to ALL threads.
DEV float wgsum256(float v, float* red) {
#pragma unroll
  for (int s = 32; s > 0; s >>= 1) v += __shfl_xor(v, s);
  if ((threadIdx.x & 63) == 0) red[threadIdx.x >> 6] = v;
  __syncthreads();
  const float t = red[0] + red[1] + red[2] + red[3];
  __syncthreads();
  return t;
}

// =========================================================================
// float4-vectorized dense layer, 256 threads.
// Thread owns 4 consecutive output cols (one dwordx4 per K-elem), cross-
// thread split-K fills remaining threads. 8-deep float4 ping-pong = 64 VGPR
// for weights total (vs 64+ scalar regs per stream before). No spill.
// =========================================================================
template<int K, int OUT, int ROWS>
DEV void denseV4(const float* __restrict__ W, const float* __restrict__ bias,
                 const float* in, int ips, float* out, int ops, int relu,
                 float* scr)
{
  constexpr int OUTG = OUT / 4;        // float4 col-groups
  constexpr int NSEG = 256 / OUTG;     // cross-thread K segments
  constexpr int KS = K / NSEG;         // K elems per segment
  constexpr int NG = KS / 8;           // 8-deep ping-pong groups
  static_assert(KS % 8 == 0 && NG >= 2, "bad shape");
  const int tid = (int)threadIdx.x;
  const int c = tid & (OUTG - 1);
  const int seg = tid / OUTG;
  const int k0 = seg * KS;
  const float4* W4 = reinterpret_cast<const float4*>(W);
  float4 w0[8], w1[8];
  float acc[ROWS][4];
#pragma unroll
  for (int r = 0; r < ROWS; ++r)
#pragma unroll
    for (int x = 0; x < 4; ++x) acc[r][x] = 0.f;
#pragma unroll
  for (int u = 0; u < 8; ++u) w0[u] = W4[(size_t)(k0 + u) * OUTG + c];
#pragma unroll
  for (int t = 1; t <= NG; ++t) {
    if (t < NG) {
#pragma unroll
      for (int u = 0; u < 8; ++u) w1[u] = W4[(size_t)(k0 + t * 8 + u) * OUTG + c];
    }
#pragma unroll
    for (int u = 0; u < 8; ++u) {
      const int kk = k0 + (t - 1) * 8 + u;
#pragma unroll
      for (int r = 0; r < ROWS; ++r) {
        const float x = in[r * ips + kk];
        acc[r][0] = fmaf(x, w0[u].x, acc[r][0]);
        acc[r][1] = fmaf(x, w0[u].y, acc[r][1]);
        acc[r][2] = fmaf(x, w0[u].z, acc[r][2]);
        acc[r][3] = fmaf(x, w0[u].w, acc[r][3]);
      }
    }
    if (t < NG) {
#pragma unroll
      for (int u = 0; u < 8; ++u) w0[u] = w1[u];
    }
  }
  float4* scr4 = reinterpret_cast<float4*>(scr);
#pragma unroll
  for (int r = 0; r < ROWS; ++r)
    scr4[(seg * ROWS + r) * OUTG + c] =
        make_float4(acc[r][0], acc[r][1], acc[r][2], acc[r][3]);
  __syncthreads();
  for (int idx = tid; idx < OUT * ROWS; idx += 256) {
    const int r = idx / OUT, j = idx % OUT;
    float v = (bias ? bias[j] : 0.f);
#pragma unroll
    for (int s = 0; s < NSEG; ++s) v += scr[(s * ROWS + r) * OUT + j];
    if (relu) v = fmaxf(v, 0.f);
    out[r * ops + j] = v;
  }
  __syncthreads();
}

// de[128] @ dec_w[128x512] vs sens -> per-thread sq-err partial. float4 cols.
DEV float declossV4(const float* de, const float* __restrict__ dec_w,
                    const float* sens, float* scr)
{
  const int tid = (int)threadIdx.x;
  const int c = tid & 127;          // col group: cols 4c..4c+3
  const int seg = tid >> 7;         // 2 K-segments x 64
  const int k0 = seg * 64;
  const float4* W4 = reinterpret_cast<const float4*>(dec_w);
  float4 w0[8], w1[8];
  float a[4] = { 0.f, 0.f, 0.f, 0.f };
#pragma unroll
  for (int u = 0; u < 8; ++u) w0[u] = W4[(size_t)(k0 + u) * 128 + c];
#pragma unroll
  for (int t = 1; t <= 8; ++t) {
    if (t < 8) {
#pragma unroll
      for (int u = 0; u < 8; ++u) w1[u] = W4[(size_t)(k0 + t * 8 + u) * 128 + c];
    }
#pragma unroll
    for (int u = 0; u < 8; ++u) {
      const float x = de[k0 + (t - 1) * 8 + u];
      a[0] = fmaf(x, w0[u].x, a[0]);
      a[1] = fmaf(x, w0[u].y, a[1]);
      a[2] = fmaf(x, w0[u].z, a[2]);
      a[3] = fmaf(x, w0[u].w, a[3]);
    }
    if (t < 8) {
#pragma unroll
      for (int u = 0; u < 8; ++u) w0[u] = w1[u];
    }
  }
  float4* scr4 = reinterpret_cast<float4*>(scr);
  scr4[seg * 128 + c] = make_float4(a[0], a[1], a[2], a[3]);
  __syncthreads();
  float lsum = 0.f;
  for (int j = tid; j < 512; j += 256) {
    const float v = scr[j] + scr[512 + j];
    const float d = v - sens[j];
    lsum = fmaf(d, d, lsum);
  }
  __syncthreads();
  return lsum;
}

// ================= K1a: action MLP first two layers =================
__global__ __launch_bounds__(128) void k_pi_h2(
    const float* __restrict__ actions,
    const float* __restrict__ w1, const float* __restrict__ b1,
    const float* __restrict__ w2, const float* __restrict__ b2,
    float* __restrict__ h2out)
{
  const int row = blockIdx.x;
  const int j = threadIdx.x;
  __shared__ float a[32];
  __shared__ float h1[128];
  if (j < 32) a[j] = actions[row * 32 + j];
  __syncthreads();
  float acc = b1[j];
#pragma unroll
  for (int i = 0; i < 32; ++i) acc = fmaf(a[i], w1[i * 128 + j], acc);
  h1[j] = fmaxf(acc, 0.f);
  __syncthreads();
  float acc2 = b2[j];
#pragma unroll 8
  for (int i = 0; i < 128; ++i) acc2 = fmaf(h1[i], w2[i * 128 + j], acc2);
  h2out[row * 128 + j] = fmaxf(acc2, 0.f);
}

// ================= K1b: h2[256,128] @ W3[128,16384] =================
__global__ __launch_bounds__(256) void k_pi_trans(
    const float* __restrict__ h2,
    const float* __restrict__ w3, const float* __restrict__ b3,
    float* __restrict__ trans)
{
  const int col = blockIdx.x * 256 + threadIdx.x;
  const int r0 = blockIdx.y * 32;
  __shared__ float h2s[32][128];
  for (int idx = threadIdx.x; idx < 32 * 128; idx += 256)
    h2s[idx >> 7][idx & 127] = h2[(size_t)(r0 + (idx >> 7)) * 128 + (idx & 127)];
  __syncthreads();
  float acc[32];
#pragma unroll
  for (int r = 0; r < 32; ++r) acc[r] = 0.f;
  for (int i = 0; i < 128; i += 8) {
    float w[8];
#pragma unroll
    for (int c = 0; c < 8; ++c) w[c] = w3[(size_t)(i + c) * 16384 + col];
#pragma unroll
    for (int r = 0; r < 32; ++r) {
      float s = acc[r];
#pragma unroll
      for (int c = 0; c < 8; ++c) s = fmaf(h2s[r][i + c], w[c], s);
      acc[r] = s;
    }
  }
  const float bv = b3[col];
#pragma unroll
  for (int r = 0; r < 32; ++r)
    trans[(size_t)(r0 + r) * 16384 + col] = acc[r] + bv;
}

// ================= K2: RNN scan with next-step prefetch =================
__global__ __launch_bounds__(512) void k_rnn(
    const float* __restrict__ trans, const float* __restrict__ rinit,
    float* __restrict__ structural)
{
  const int b = blockIdx.x;
  const int tid = threadIdx.x;
  const int j = tid & 127, seg = tid >> 7;
  __shared__ float h[128];
  __shared__ float part[4][128];
  __shared__ float ssq;
  if (tid < 128) h[tid] = rinit[tid];
  __syncthreads();
  if (tid < 64) {
    float v = h[tid] * h[tid] + h[tid + 64] * h[tid + 64];
#pragma unroll
    for (int s = 32; s > 0; s >>= 1) v += __shfl_xor(v, s);
    if (tid == 0) ssq = v;
  }
  __syncthreads();
  if (tid < 128) h[tid] /= fmaxf(sqrtf(ssq), 1e-12f);
  __syncthreads();

  float cur[32], nxt[32];
  {
    const float* T0 = trans + ((size_t)(b * 32) << 14);
#pragma unroll
    for (int k = 0; k < 32; ++k) cur[k] = T0[(size_t)(seg * 32 + k) * 128 + j];
  }
  for (int t = 0; t < 32; ++t) {
    if (t < 31) {
      const float* Tn = trans + ((size_t)(b * 32 + t + 1) << 14);
#pragma unroll
      for (int k = 0; k < 32; ++k) nxt[k] = Tn[(size_t)(seg * 32 + k) * 128 + j];
    }
    float acc = 0.f;
#pragma unroll
    for (int k = 0; k < 32; ++k) acc = fmaf(h[seg * 32 + k], cur[k], acc);
    part[seg][j] = acc;
    __syncthreads();
    if (tid < 128) {
      float r = fmaxf(part[0][j] + part[1][j] + part[2][j] + part[3][j], 0.f);
      part[0][j] = r;
    }
    __syncthreads();
    if (tid < 64) {
      float v = part[0][tid] * part[0][tid] + part[0][tid + 64] * part[0][tid + 64];
#pragma unroll
      for (int s = 32; s > 0; s >>= 1) v += __shfl_xor(v, s);
      if (tid == 0) ssq = v;
    }
    __syncthreads();
    if (tid < 128) {
      const float nv = part[0][j] / fmaxf(sqrtf(ssq), 1e-12f);
      h[j] = nv;
      structural[(size_t)(b * 32 + t) * 128 + j] = nv;
    }
    __syncthreads();
    if (t < 31) {
#pragma unroll
      for (int k = 0; k < 32; ++k) cur[k] = nxt[k];
    }
  }
}

// ================= kChain: enc + r1..r4 + pv + all losses + keys/vals/hp =================
__global__ __launch_bounds__(256) void kChain(
    const float* __restrict__ sensory, const float* __restrict__ structural_,
    const float* __restrict__ enc_w, const float* __restrict__ wq,
    const float* __restrict__ dec_w,
    const float* __restrict__ mw1, const float* __restrict__ mb1,
    const float* __restrict__ mw2, const float* __restrict__ mb2,
    const float* __restrict__ mw3, const float* __restrict__ mb3,
    const float* __restrict__ ow1, const float* __restrict__ ob1,
    const float* __restrict__ ow2, const float* __restrict__ ob2,
    const float* __restrict__ ow3, const float* __restrict__ ob3,
    const float* __restrict__ vw1, const float* __restrict__ vb1,
    const float* __restrict__ vw2, const float* __restrict__ vb2,
    const float* __restrict__ vw3, const float* __restrict__ vb3,
    const float* __restrict__ wk, const float* __restrict__ wv,
    const float* __restrict__ w_hp, const float* __restrict__ ir,
    float* __restrict__ gKeys, float* __restrict__ gVals,
    float* __restrict__ gHp, float* __restrict__ lossPart)
{
  const int g = blockIdx.x, tid = threadIdx.x;
  __shared__ float sens[512], sRow[128], eRow[128], dgsRow[128], cRow[128], infRow[128];
  __shared__ float cbuf[256];
  __shared__ float actA[2 * OPS], actB[2 * OPS];
  __shared__ float4 scr4buf[512];                 // 2048 floats, 16B aligned
  __shared__ float red[4];
  float* scr = reinterpret_cast<float*>(scr4buf);

  for (int i = tid; i < 512; i += 256) sens[i] = sensory[(size_t)g * 512 + i];
  if (tid < 128) sRow[tid] = structural_[(size_t)g * 128 + tid];
  __syncthreads();

  // enc = sens @ enc_w   (K=512 -> 128)
  denseV4<512, 128, 1>(enc_w, nullptr, sens, 0, eRow, 0, 0, scr);

  // ---- retrieve 1+2 paired: q1 = sRow@wq_top, q2 = eRow@wq_bot ----
  denseV4<128, 128, 1>(wq, nullptr, sRow, 0, actA, 0, 0, scr);
  denseV4<128, 128, 1>(wq + 128 * 128, nullptr, eRow, 0, actA + OPS, 0, 0, scr);
  denseV4<128, 256, 2>(mw1, mb1, actA, OPS, actB, OPS, 1, scr);
  denseV4<256, 256, 2>(mw2, mb2, actB, OPS, actA, OPS, 1, scr);
  denseV4<256, 128, 2>(mw3, mb3, actA, OPS, actB, OPS, 0, scr);
  denseV4<128, 256, 2>(ow1, ob1, actB, OPS, actA, OPS, 1, scr);
  denseV4<256, 256, 2>(ow2, ob2, actA, OPS, actB, OPS, 1, scr);
  denseV4<256, 256, 2>(ow3, ob3, actB, OPS, actA, OPS, 0, scr);
  // actA row0 = [dgs|dec_enc], row1 = [dec_s2|*]
  float lrel = 0.f;
  if (tid < 128) {
    dgsRow[tid] = actA[tid];
    const float d = actA[OPS + tid] - sRow[tid];
    lrel = d * d;
  }
  const float relT = wgsum256(lrel, red);
  if (tid == 0) lossPart[256 + g] = relT;
  const float genT = wgsum256(declossV4(&actA[128], dec_w, sens, scr), red);
  if (tid == 0) lossPart[g] = genT;

  // ---- retrieve 3 ----
  cbuf[tid] = (tid < 128) ? dgsRow[tid] : eRow[tid - 128];
  __syncthreads();
  denseV4<256, 128, 1>(wq, nullptr, cbuf, 0, actA, 0, 0, scr);    // q3
  denseV4<128, 256, 1>(mw1, mb1, actA, 0, actB, 0, 1, scr);
  denseV4<256, 256, 1>(mw2, mb2, actB, 0, actA, 0, 1, scr);
  denseV4<256, 128, 1>(mw3, mb3, actA, 0, actB, 0, 0, scr);
  denseV4<128, 256, 1>(ow1, ob1, actB, 0, actA, 0, 1, scr);
  denseV4<256, 256, 1>(ow2, ob2, actA, 0, actB, 0, 1, scr);
  denseV4<256, 256, 1>(ow3, ob3, actB, 0, actA, 0, 0, scr);       // [corr|corr_e]
  float ls = 0.f;
  if (tid < 128) {
    cRow[tid] = actA[tid];
    const float d = actA[128 + tid] - eRow[tid];
    ls = d * d;
  }
  const float sseV = wgsum256(ls, red);

  // ---- pred_var ----
  cbuf[tid] = (tid < 128) ? cRow[tid] : dgsRow[tid - 128];
  __syncthreads();
  denseV4<256, 256, 1>(vw1, vb1, cbuf, 0, actB, 0, 0, scr);
  actB[tid] = fmaxf(actB[tid] + sseV * vw1[(size_t)256 * 256 + tid], 0.f);
  __syncthreads();
  denseV4<256, 256, 1>(vw2, vb2, actB, 0, actA, 0, 1, scr);
  denseV4<256, 128, 1>(vw3, vb3, actA, 0, actB, 0, 0, scr);       // pv
  const float sig = sigm(ir[0]);
  float lc = 0.f;
  if (tid < 128) {
    const float diff = (cRow[tid] - dgsRow[tid]) * sig * actB[tid];
    infRow[tid] = dgsRow[tid] + diff;
    lc = diff * diff;
  }
  const float consT = wgsum256(lc, red);
  if (tid == 0) lossPart[512 + g] = consT;
  __syncthreads();

  // ---- retrieve 4 ----
  denseV4<128, 128, 1>(wq, nullptr, infRow, 0, actA, 0, 0, scr);  // q4
  denseV4<128, 256, 1>(mw1, mb1, actA, 0, actB, 0, 1, scr);
  denseV4<256, 256, 1>(mw2, mb2, actB, 0, actA, 0, 1, scr);
  denseV4<256, 128, 1>(mw3, mb3, actA, 0, actB, 0, 0, scr);
  denseV4<128, 256, 1>(ow1, ob1, actB, 0, actA, 0, 1, scr);
  denseV4<256, 256, 1>(ow2, ob2, actA, 0, actB, 0, 1, scr);
  denseV4<256, 256, 1>(ow3, ob3, actB, 0, actA, 0, 0, scr);       // [finalS|inf_e]
  const float infT = wgsum256(declossV4(&actA[128], dec_w, sens, scr), red);
  if (tid == 0) lossPart[768 + g] = infT;

  // ---- keys / vals / hp ----
  cbuf[tid] = (tid < 128) ? actA[tid] : eRow[tid - 128];
  __syncthreads();
  denseV4<256, 128, 1>(wk, nullptr, cbuf, 0, gKeys + (size_t)g * 128, 0, 0, scr);
  denseV4<256, 128, 1>(wv, nullptr, cbuf, 0, gVals + (size_t)g * 128, 0, 0, scr);
  const int c = tid >> 6, l = tid & 63;
  float acc = 0.f;
  if (c < 3) {
    for (int i = l; i < 256; i += 64)
      acc = fmaf(cbuf[i], w_hp[i * 3 + c], acc);
  }
#pragma unroll
  for (int s = 32; s > 0; s >>= 1) acc += __shfl_xor(acc, s);
  if (c < 3 && l == 0) gHp[(size_t)g * 4 + c] = acc;
}

// ================= kD: meta fwd/bwd (blocks 0-255) + coef scan (block 256) =================
__global__ __launch_bounds__(256) void kD(
    const float* __restrict__ gKeys, const float* __restrict__ gVals,
    const float* __restrict__ gHp,
    const float* __restrict__ mw1, const float* __restrict__ mb1,
    const float* __restrict__ mw2, const float* __restrict__ mb2,
    const float* __restrict__ mw3, const float* __restrict__ mb3,
    float* __restrict__ ws_h1, float* __restrict__ ws_h2,
    float* __restrict__ ws_d1, float* __restrict__ ws_d2, float* __restrict__ ws_d3,
    float* __restrict__ wA, float* __restrict__ wU, float* __restrict__ Ft)
{
  const int tid = threadIdx.x;
  __shared__ float kRow[128], vRow[128];
  __shared__ float actA[256], actB[256], d3R[128], d2R[256];
  __shared__ float4 scr4buf[512];
  __shared__ float lr[256], sf[256], sb[256];
  float* scr = reinterpret_cast<float*>(scr4buf);
  if (blockIdx.x == 256) {
    lr[tid] = gHp[(size_t)tid * 4 + 0];
    sf[tid] = sigm(gHp[(size_t)tid * 4 + 1]);
    sb[tid] = sigm(gHp[(size_t)tid * 4 + 2]);
    __syncthreads();
    if (tid < 8) {
      const int b = tid;
      float cB = 1.f, cF = 1.f, Bv = 1.f;
      wU[b * 32 + 31] = lr[b * 32 + 31];
      wA[b * 32 + 31] = lr[b * 32 + 31];
      for (int t = 30; t >= 0; --t) {
        cB = sb[b * 32 + t + 1] * cB;
        cF = sf[b * 32 + t + 1] * cF;
        Bv = cF + sb[b * 32 + t + 1] * Bv;
        wU[b * 32 + t] = lr[b * 32 + t] * cB;
        wA[b * 32 + t] = lr[b * 32 + t] * Bv;
      }
      float ft = 1.f;
      for (int t = 0; t < 32; ++t) ft *= sf[b * 32 + t];
      Ft[b] = ft;
    }
    return;
  }
  const int g = blockIdx.x;
  if (tid < 128) kRow[tid] = gKeys[(size_t)g * 128 + tid];
  else vRow[tid - 128] = gVals[(size_t)g * 128 + (tid - 128)];
  __syncthreads();
  denseV4<128, 256, 1>(mw1, mb1, kRow, 0, actA, 0, 1, scr);
  ws_h1[(size_t)g * 256 + tid] = actA[tid];
  denseV4<256, 256, 1>(mw2, mb2, actA, 0, actB, 0, 1, scr);
  ws_h2[(size_t)g * 256 + tid] = actB[tid];
  denseV4<256, 128, 1>(mw3, mb3, actB, 0, d3R, 0, 0, scr);
  if (tid < 128) {
    const float d = (d3R[tid] - vRow[tid]) * (2.f / 128.f);
    d3R[tid] = d;
    ws_d3[(size_t)g * 128 + tid] = d;
  }
  __syncthreads();
  // d2 = relu'(h2) * (mw3 row j . d3)
  {
    const int j = tid;
    float acc = 0.f;
    for (int jc = 0; jc < 128; jc += 4) {
      const float4 w = *reinterpret_cast<const float4*>(&mw3[(size_t)j * 128 + jc]);
      acc = fmaf(w.x, d3R[jc + 0], acc);
      acc = fmaf(w.y, d3R[jc + 1], acc);
      acc = fmaf(w.z, d3R[jc + 2], acc);
      acc = fmaf(w.w, d3R[jc + 3], acc);
    }
    const float v = (actB[j] > 0.f) ? acc : 0.f;
    d2R[j] = v;
    ws_d2[(size_t)g * 256 + j] = v;
  }
  __syncthreads();
  // d1 = relu'(h1) * (mw2 row j . d2)
  {
    const int j = tid;
    float acc = 0.f;
    for (int jc = 0; jc < 256; jc += 4) {
      const float4 w = *reinterpret_cast<const float4*>(&mw2[(size_t)j * 256 + jc]);
      acc = fmaf(w.x, d2R[jc + 0], acc);
      acc = fmaf(w.y, d2R[jc + 1], acc);
      acc = fmaf(w.z, d2R[jc + 2], acc);
      acc = fmaf(w.w, d2R[jc + 3], acc);
    }
    ws_d1[(size_t)g * 256 + j] = (actA[j] > 0.f) ? acc : 0.f;
  }
}

// ================= kW: outer products + bias + final =================
DEV void outer_body(const float* __restrict__ L, int Lld,
                    const float* __restrict__ D, int Dld,
                    const float* __restrict__ P,
                    const float* __restrict__ wA, const float* __restrict__ wU,
                    const float* __restrict__ Ftot,
                    float* __restrict__ out, size_t regionOff, int J,
                    int b, int i0, float* __restrict__ wAk, float* __restrict__ wUk)
{
  const int tid = threadIdx.x;
  for (int idx = tid; idx < 1024; idx += 256) {
    const int t = idx >> 5, ii = idx & 31;
    const float kv = L[(size_t)(b * 32 + t) * Lld + i0 + ii];
    wAk[t * 33 + ii] = wA[b * 32 + t] * kv;
    wUk[t * 33 + ii] = wU[b * 32 + t] * kv;
  }
  __syncthreads();
  const int j = (J == 256) ? tid : (tid & 127);
  const int g2 = (J == 256) ? 0 : (tid >> 7);
  const int span = (J == 256) ? 32 : 16;
  const int iBeg = g2 * span;
  float dv[32];
#pragma unroll
  for (int t = 0; t < 32; ++t) dv[t] = D[(size_t)(b * 32 + t) * Dld + j];
  const float ft = Ftot[b];
  float* ob = out + 1 + (size_t)b * (2 * W_TOT);
  for (int ii = iBeg; ii < iBeg + span; ++ii) {
    float aA = 0.f, aU = 0.f;
#pragma unroll
    for (int t = 0; t < 32; ++t) {
      aA = fmaf(wAk[t * 33 + ii], dv[t], aA);
      aU = fmaf(wUk[t * 33 + ii], dv[t], aU);
    }
    const int i = i0 + ii;
    const size_t w = regionOff + (size_t)i * J + j;
    ob[w] = ft * P[(size_t)i * J + j] - aA;
    ob[W_TOT + w] = aU;
  }
}

__global__ __launch_bounds__(256) void kW(
    const float* __restrict__ keys, const float* __restrict__ h1,
    const float* __restrict__ h2, const float* __restrict__ d1,
    const float* __restrict__ d2, const float* __restrict__ d3,
    const float* __restrict__ mw1, const float* __restrict__ mb1,
    const float* __restrict__ mw2, const float* __restrict__ mb2,
    const float* __restrict__ mw3, const float* __restrict__ mb3,
    const float* __restrict__ wA, const float* __restrict__ wU,
    const float* __restrict__ Ft, const float* __restrict__ lossPart,
    float* __restrict__ out)
{
  __shared__ float wAk[32 * 33], wUk[32 * 33];
  __shared__ float red[4];
  const int bid = blockIdx.x;
  const int tid = threadIdx.x;
  if (bid < 32) {
    outer_body(keys, 128, d1, 256, mw1, wA, wU, Ft, out, OFF_W1, 256,
               bid >> 2, (bid & 3) * 32, wAk, wUk);
  } else if (bid < 96) {
    const int x = bid - 32;
    outer_body(h1, 256, d2, 256, mw2, wA, wU, Ft, out, OFF_W2, 256,
               x >> 3, (x & 7) * 32, wAk, wUk);
  } else if (bid < 160) {
    const int x = bid - 96;
    outer_body(h2, 256, d3, 128, mw3, wA, wU, Ft, out, OFF_W3, 128,
               x >> 3, (x & 7) * 32, wAk, wUk);
  } else if (bid < 168) {
    const int b = bid - 160;
    const float ft = Ft[b];
    float* ob = out + 1 + (size_t)b * (2 * W_TOT);
    for (int idx = tid; idx < 640; idx += 256) {
      const float* D; int ld, j; size_t off; float pv;
      if (idx < 256)      { D = d1; ld = 256; j = idx;       off = OFF_B1; pv = mb1[j]; }
      else if (idx < 512) { D = d2; ld = 256; j = idx - 256; off = OFF_B2; pv = mb2[j]; }
      else                { D = d3; ld = 128; j = idx - 512; off = OFF_B3; pv = mb3[j]; }
      float aA = 0.f, aU = 0.f;
#pragma unroll
      for (int t = 0; t < 32; ++t) {
        const float dv = D[(size_t)(b * 32 + t) * ld + j];
        aA = fmaf(wA[b * 32 + t], dv, aA);
        aU = fmaf(wU[b * 32 + t], dv, aU);
      }
      ob[off + j] = ft * pv - aA;
      ob[W_TOT + off + j] = aU;
    }
  } else {
    const int c = tid >> 6, l = tid & 63;
    float v = lossPart[c * 256 + l] + lossPart[c * 256 + 64 + l] +
              lossPart[c * 256 + 128 + l] + lossPart[c * 256 + 192 + l];
#pragma unroll
    for (int s = 32; s > 0; s >>= 1) v += __shfl_xor(v, s);
    if (l == 0) red[c] = v;
    __syncthreads();
    if (tid == 0) {
      const float i1 = 1.f / (256.f * 512.f);
      const float i2 = 1.f / (256.f * 128.f);
      out[0] = red[0] * i1 + 2.f * red[1] * i2 + red[2] * i2 + red[3] * i1;
    }
  }
}

// ================= launch =================
extern "C" void kernel_launch(void* const* d_in, const int* in_sizes, int n_in,
                              void* d_out, int out_size, void* d_ws, size_t ws_size,
                              hipStream_t stream)
{
  const float* sensory = (const float*)d_in[0];
  const float* actions = (const float*)d_in[1];
  const float* enc_w = (const float*)d_in[2];
  const float* dec_w = (const float*)d_in[3];
  const float* pi_w1 = (const float*)d_in[4];
  const float* pi_b1 = (const float*)d_in[5];
  const float* pi_w2 = (const float*)d_in[6];
  const float* pi_b2 = (const float*)d_in[7];
  const float* pi_w3 = (const float*)d_in[8];
  const float* pi_b3 = (const float*)d_in[9];
  const float* rinit = (const float*)d_in[10];
  const float* wq = (const float*)d_in[11];
  const float* wk = (const float*)d_in[12];
  const float* wv = (const float*)d_in[13];
  const float* w_hp = (const float*)d_in[14];
  const float* mw1 = (const float*)d_in[15]; const float* mb1 = (const float*)d_in[16];
  const float* mw2 = (const float*)d_in[17]; const float* mb2 = (const float*)d_in[18];
  const float* mw3 = (const float*)d_in[19]; const float* mb3 = (const float*)d_in[20];
  const float* ow1 = (const float*)d_in[21]; const float* ob1 = (const float*)d_in[22];
  const float* ow2 = (const float*)d_in[23]; const float* ob2 = (const float*)d_in[24];
  const float* ow3 = (const float*)d_in[25]; const float* ob3 = (const float*)d_in[26];
  const float* vw1 = (const float*)d_in[27]; const float* vb1 = (const float*)d_in[28];
  const float* vw2 = (const float*)d_in[29]; const float* vb2 = (const float*)d_in[30];
  const float* vw3 = (const float*)d_in[31]; const float* vb3 = (const float*)d_in[32];
  const float* ir  = (const float*)d_in[33];

  float* ws  = (float*)d_ws;
  float* out = (float*)d_out;

  float* lossP = ws + P_LOSS;
  float* wA = ws + P_WA; float* wU = ws + P_WU; float* Ft = ws + P_FT;
  float* hp = ws + P_HP;
  float* h2pi = ws + P_H2PI;
  float* keys = ws + P_KEYS;
  float* vals = ws + P_VALS;
  float* d3s = ws + P_D3;
  float* h1s = ws + P_H1;
  float* h2s = ws + P_H2;
  float* d1s = ws + P_D1;
  float* d2s = ws + P_D2;
  float* structural = ws + P_STRUCT;
  float* trans = ws + P_TRANS;

  hipLaunchKernelGGL(k_pi_h2, dim3(256), dim3(128), 0, stream,
                     actions, pi_w1, pi_b1, pi_w2, pi_b2, h2pi);
  hipLaunchKernelGGL(k_pi_trans, dim3(64, 8), dim3(256), 0, stream,
                     h2pi, pi_w3, pi_b3, trans);
  hipLaunchKernelGGL(k_rnn, dim3(8), dim3(512), 0, stream, trans, rinit, structural);
  hipLaunchKernelGGL(kChain, dim3(256), dim3(256), 0, stream,
                     sensory, structural, enc_w, wq, dec_w,
                     mw1, mb1, mw2, mb2, mw3, mb3,
                     ow1, ob1, ow2, ob2, ow3, ob3,
                     vw1, vb1, vw2, vb2, vw3, vb3,
                     wk, wv, w_hp, ir, keys, vals, hp, lossP);
  hipLaunchKernelGGL(kD, dim3(257), dim3(256), 0, stream,
                     keys, vals, hp, mw1, mb1, mw2, mb2, mw3, mb3,
                     h1s, h2s, d1s, d2s, d3s, wA, wU, Ft);
  hipLaunchKernelGGL(kW, dim3(169), dim3(256), 0, stream,
                     keys, h1s, h2s, d1s, d2s, d3s,
                     mw1, mb1, mw2, mb2, mw3, mb3,
                     wA, wU, Ft, lossP, out);
}